// Round 2
// baseline (146.683 us; speedup 1.0000x reference)
//
#include <hip/hip_runtime.h>
#include <math.h>

// Problem constants (from reference)
#define BB   4
#define NN   40
#define TT   64
#define NIN  4
#define NEMB 32
#define NHID 64
#define NG   256   // 4*NHID
#define EPSW 1e-5f

__device__ __forceinline__ float fast_sigmoid(float x) {
    return __fdividef(1.0f, 1.0f + __expf(-x));
}
__device__ __forceinline__ float fast_tanh(float x) {
    return __fdividef(2.0f, 1.0f + __expf(-2.0f * x)) - 1.0f;
}

// ---------------------------------------------------------------------------
// Kernel 1: per-(b,n) LSTM chain + temporal-attention pooling (output cols 0..63)
// Grid: 160 blocks (b*40+n), 256 threads (one per gate row).
//
// Key structure (vs round-0):
//  * embedding folded into gate weights: gx[t,g] = bc_g + x[t,:4] . Wc[g,:4]
//    where Wc = W_ih @ W_emb, bc = b_ih + b_hh + W_ih @ b_emb.  All 64 gx
//    values live in registers (step loop fully unrolled).
//  * ONE barrier per step: every wave redundantly computes the c/h update
//    (bit-identical across waves -> racing identical-value s_h writes are
//    benign); s_act double-buffered by t&1 to close the act-read hazard.
//  * no global stores inside the serial loop (hs dumped from LDS at the end).
// ---------------------------------------------------------------------------
__global__ __launch_bounds__(256)
void k_lstm(const float* __restrict__ inputs,
            const float* __restrict__ W_emb,
            const float* __restrict__ b_emb,
            const float* __restrict__ W_ih,
            const float* __restrict__ W_hh,
            const float* __restrict__ b_ih,
            const float* __restrict__ b_hh,
            const float* __restrict__ W_att,
            float* __restrict__ out,
            float* __restrict__ hs_g)
{
    __shared__ __align__(16) float s_x[TT * NIN];          // raw inputs (t-major)
    __shared__ __align__(16) float s_h[NHID];              // current hidden state
    __shared__ __align__(16) float s_act[2][NG];           // gate acts, double-buffered
    __shared__ __align__(16) float s_hs[TT * (NHID + 1)];  // all h, pad 65
    __shared__ __align__(16) float s_war[NHID];            // W_att[0,64:128]
    __shared__ __align__(16) float s_p[TT];                // softmax weights

    const int m   = blockIdx.x;       // b*NN + n
    const int tid = threadIdx.x;
    const int g   = tid;              // gate row 0..255
    const int j   = tid & 63;         // hidden index this thread updates
    const int gtype = g >> 6;         // 0:i 1:f 2:g 3:o (wave-uniform)

    // stage raw inputs (256 floats, coalesced)
    s_x[tid] = inputs[m * (TT * NIN) + tid];
    if (tid < NHID) { s_war[tid] = W_att[NHID + tid]; s_h[tid] = 0.0f; }

    // ---- fold embedding into this thread's gate row: Wc[4], bc ----
    float wcx = 0.f, wcy = 0.f, wcz = 0.f, wcw = 0.f;
    float bc  = b_ih[g] + b_hh[g];
    {
        const float4* wih4  = (const float4*)(W_ih + g * NEMB);
        const float4* wemb4 = (const float4*)W_emb;   // row e (4 floats)
        #pragma unroll
        for (int e4 = 0; e4 < NEMB / 4; ++e4) {
            float4 wv = wih4[e4];
            float4 m0 = wemb4[4 * e4 + 0];
            float4 m1 = wemb4[4 * e4 + 1];
            float4 m2 = wemb4[4 * e4 + 2];
            float4 m3 = wemb4[4 * e4 + 3];
            wcx += wv.x * m0.x + wv.y * m1.x + wv.z * m2.x + wv.w * m3.x;
            wcy += wv.x * m0.y + wv.y * m1.y + wv.z * m2.y + wv.w * m3.y;
            wcz += wv.x * m0.z + wv.y * m1.z + wv.z * m2.z + wv.w * m3.z;
            wcw += wv.x * m0.w + wv.y * m1.w + wv.z * m2.w + wv.w * m3.w;
            bc  += wv.x * b_emb[4 * e4 + 0] + wv.y * b_emb[4 * e4 + 1]
                 + wv.z * b_emb[4 * e4 + 2] + wv.w * b_emb[4 * e4 + 3];
        }
    }

    // ---- this thread's recurrent weight row (64 floats -> VGPRs) ----
    float whh[NHID];
    {
        const float4* q4 = (const float4*)(W_hh + g * NHID);
        #pragma unroll
        for (int k = 0; k < NHID / 4; ++k) {
            float4 v = q4[k];
            whh[4 * k + 0] = v.x; whh[4 * k + 1] = v.y;
            whh[4 * k + 2] = v.z; whh[4 * k + 3] = v.w;
        }
    }

    __syncthreads();   // s_x, s_h ready

    // ---- precompute gx[t] (registers; step loop fully unrolled below) ----
    float gxv[TT];
    {
        const float4* x4 = (const float4*)s_x;
        #pragma unroll
        for (int t = 0; t < TT; ++t) {
            float4 x = x4[t];
            gxv[t] = bc + x.x * wcx + x.y * wcy + x.z * wcz + x.w * wcw;
        }
    }

    // ---- recurrence: 64 steps, ONE barrier each ----
    float c = 0.0f;    // redundant per-wave copy of c_j
    #pragma unroll
    for (int t = 0; t < TT; ++t) {
        const int p = t & 1;
        // gate pre-activation: gx + h . whh (4 independent chains)
        float v0 = gxv[t], v1 = 0.f, v2 = 0.f, v3 = 0.f;
        const float4* h4 = (const float4*)s_h;
        #pragma unroll
        for (int k = 0; k < NHID / 4; ++k) {
            float4 a = h4[k];
            v0 += a.x * whh[4 * k + 0];
            v1 += a.y * whh[4 * k + 1];
            v2 += a.z * whh[4 * k + 2];
            v3 += a.w * whh[4 * k + 3];
        }
        const float v = (v0 + v1) + (v2 + v3);
        const float a = (gtype == 2) ? fast_tanh(v) : fast_sigmoid(v);
        s_act[p][g] = a;
        __syncthreads();

        // redundant update in every wave (bit-identical across waves)
        const float ig = s_act[p][j];
        const float fg = s_act[p][NHID + j];
        const float gg = s_act[p][2 * NHID + j];
        const float og = s_act[p][3 * NHID + j];
        c = fg * c + ig * gg;
        const float h = og * fast_tanh(c);
        s_h[j] = h;                                   // identical values race: benign
        if (tid < NHID) s_hs[t * (NHID + 1) + j] = h; // wave 0 records history
        // no barrier: each wave reads back its OWN s_h writes next step;
        // other waves' writes are identical 32-bit values.
    }
    __syncthreads();   // s_hs complete

    // ---- dump hs to global for kernel 2 (coalesced) ----
    #pragma unroll
    for (int idx = tid; idx < TT * NHID; idx += 256) {
        const int t = idx >> 6, h = idx & 63;
        hs_g[m * (TT * NHID) + idx] = s_hs[t * (NHID + 1) + h];
    }

    // ---- temporal attention pooling (softmax over t, i-independent) ----
    if (tid < TT) {
        const int t = tid;
        float r = 0.0f;
        #pragma unroll
        for (int k = 0; k < NHID; ++k)
            r += s_hs[t * (NHID + 1) + k] * s_war[k];
        float mx = r;
        #pragma unroll
        for (int off = 32; off >= 1; off >>= 1)
            mx = fmaxf(mx, __shfl_xor(mx, off));
        const float e = __expf(r - mx);
        float s = e;
        #pragma unroll
        for (int off = 32; off >= 1; off >>= 1)
            s += __shfl_xor(s, off);
        s_p[t] = __fdividef(e, s);
    }
    __syncthreads();

    if (tid < NHID) {
        float acc = 0.0f;
        #pragma unroll
        for (int t = 0; t < TT; ++t)
            acc += s_p[t] * s_hs[t * (NHID + 1) + tid];
        out[m * (2 * NHID) + tid] = fast_tanh(acc);
    }
}

// ---------------------------------------------------------------------------
// Kernel 2: spatial inverse-distance aggregation (output cols 64..127)
// chsum[b,i,h] = sum_t sum_{j!=i} hs[b,j,t,h] / (dist(i,j,t)+eps)
// Grid: 160 blocks (b*40+i), 256 threads = (t-quarter q, h).
// ---------------------------------------------------------------------------
__global__ __launch_bounds__(256)
void k_spatial(const float* __restrict__ inputs,
               const float* __restrict__ hs_g,
               float* __restrict__ out)
{
    __shared__ float s_w[TT * NN];          // 2560 inverse-distance weights
    __shared__ float s_part[4 * NHID];

    const int bi  = blockIdx.x;
    const int b   = bi / NN;
    const int i   = bi - b * NN;
    const int tid = threadIdx.x;

    for (int idx = tid; idx < TT * NN; idx += 256) {
        const int t = idx / NN;
        const int j = idx - t * NN;
        const float* pi = inputs + ((b * NN + i) * TT + t) * NIN;
        const float* pj = inputs + ((b * NN + j) * TT + t) * NIN;
        const float dx = pi[0] - pj[0];
        const float dy = pi[1] - pj[1];
        const float d  = sqrtf(dx * dx + dy * dy);
        s_w[idx] = (j == i) ? 0.0f : __fdividef(1.0f, d + EPSW);
    }
    __syncthreads();

    const int h = tid & 63;
    const int q = tid >> 6;          // t-quarter

    const float* base = hs_g + (size_t)b * NN * TT * NHID + h;
    float a0 = 0.f, a1 = 0.f, a2 = 0.f, a3 = 0.f;
    for (int t = q * 16; t < q * 16 + 16; ++t) {
        const float* hp = base + t * NHID;
        const float* wp = s_w + t * NN;
        #pragma unroll
        for (int j = 0; j < NN; j += 4) {
            a0 += wp[j + 0] * hp[(size_t)(j + 0) * TT * NHID];
            a1 += wp[j + 1] * hp[(size_t)(j + 1) * TT * NHID];
            a2 += wp[j + 2] * hp[(size_t)(j + 2) * TT * NHID];
            a3 += wp[j + 3] * hp[(size_t)(j + 3) * TT * NHID];
        }
    }
    s_part[q * NHID + h] = (a0 + a1) + (a2 + a3);
    __syncthreads();

    if (tid < NHID) {
        const float s = s_part[tid] + s_part[NHID + tid] +
                        s_part[2 * NHID + tid] + s_part[3 * NHID + tid];
        out[bi * (2 * NHID) + NHID + tid] = fast_tanh(s);
    }
}

extern "C" void kernel_launch(void* const* d_in, const int* in_sizes, int n_in,
                              void* d_out, int out_size, void* d_ws, size_t ws_size,
                              hipStream_t stream) {
    const float* inputs = (const float*)d_in[0];
    // d_in[1..4]: rel_rec / rel_send / rel_rec_t / rel_send_t (one-hot, folded)
    const float* W_emb  = (const float*)d_in[5];
    const float* b_emb  = (const float*)d_in[6];
    const float* W_ih   = (const float*)d_in[7];
    const float* W_hh   = (const float*)d_in[8];
    const float* b_ih   = (const float*)d_in[9];
    const float* b_hh   = (const float*)d_in[10];
    const float* W_att  = (const float*)d_in[11];
    // d_in[12] = b_att: cancels in the softmax, unused.

    float* outp = (float*)d_out;
    float* hs_g = (float*)d_ws;   // 160*64*64 floats = 2.62 MB

    hipLaunchKernelGGL(k_lstm, dim3(BB * NN), dim3(256), 0, stream,
                       inputs, W_emb, b_emb, W_ih, W_hh, b_ih, b_hh, W_att,
                       outp, hs_g);
    hipLaunchKernelGGL(k_spatial, dim3(BB * NN), dim3(256), 0, stream,
                       inputs, hs_g, outp);
}

// Round 3
// 138.569 us; speedup vs baseline: 1.0586x; 1.0586x over previous
//
#include <hip/hip_runtime.h>
#include <math.h>

// Problem constants (from reference)
#define BB   4
#define NN   40
#define TT   64
#define NIN  4
#define NEMB 32
#define NHID 64
#define NG   256   // 4*NHID
#define EPSW 1e-5f

__device__ __forceinline__ float fast_sigmoid(float x) {
    return __fdividef(1.0f, 1.0f + __expf(-x));
}
__device__ __forceinline__ float fast_tanh(float x) {
    return __fdividef(2.0f, 1.0f + __expf(-2.0f * x)) - 1.0f;
}

// ---------------------------------------------------------------------------
// Kernel 1: per-(b,n) LSTM chain + temporal-attention pooling (output cols 0..63)
// Grid: 160 blocks (b*40+n), 256 threads (one per gate row).
//
//  * embedding folded into gate weights: gx[t,g] = bc_g + x[t,:4].Wc[g,:4]
//    (Wc = W_ih @ W_emb), computed IN-LOOP (4 FMAs) — round-1's register
//    array gxv[64] forced a full unroll -> 8K-instr body -> I-cache thrash
//    (FETCH_SIZE +455KB, VALUBusy 14%->6.7%). Loop is now rolled (unroll 1).
//  * ONE barrier per step: every wave redundantly computes the c/h update
//    (bit-identical across waves; racing identical-value s_h writes benign);
//    s_act double-buffered by t&1; compiler-level memory fence after the
//    s_h write prevents read hoisting.
//  * no global stores inside the serial loop (hs dumped from LDS at the end).
// ---------------------------------------------------------------------------
__global__ __launch_bounds__(256)
void k_lstm(const float* __restrict__ inputs,
            const float* __restrict__ W_emb,
            const float* __restrict__ b_emb,
            const float* __restrict__ W_ih,
            const float* __restrict__ W_hh,
            const float* __restrict__ b_ih,
            const float* __restrict__ b_hh,
            const float* __restrict__ W_att,
            float* __restrict__ out,
            float* __restrict__ hs_g)
{
    __shared__ __align__(16) float s_x[TT * NIN];          // raw inputs (t-major)
    __shared__ __align__(16) float s_h[NHID];              // current hidden state
    __shared__ __align__(16) float s_act[2][NG];           // gate acts, double-buffered
    __shared__ __align__(16) float s_hs[TT * (NHID + 1)];  // all h, pad 65
    __shared__ __align__(16) float s_war[NHID];            // W_att[0,64:128]
    __shared__ __align__(16) float s_p[TT];                // softmax weights

    const int m   = blockIdx.x;       // b*NN + n
    const int tid = threadIdx.x;
    const int g   = tid;              // gate row 0..255
    const int j   = tid & 63;         // hidden index this thread updates
    const int gtype = g >> 6;         // 0:i 1:f 2:g 3:o (wave-uniform)

    // stage raw inputs (256 floats, coalesced)
    s_x[tid] = inputs[m * (TT * NIN) + tid];
    if (tid < NHID) { s_war[tid] = W_att[NHID + tid]; s_h[tid] = 0.0f; }

    // ---- fold embedding into this thread's gate row: Wc[4], bc ----
    float wcx = 0.f, wcy = 0.f, wcz = 0.f, wcw = 0.f;
    float bc  = b_ih[g] + b_hh[g];
    {
        const float4* wih4  = (const float4*)(W_ih + g * NEMB);
        const float4* wemb4 = (const float4*)W_emb;   // row e (4 floats)
        #pragma unroll
        for (int e4 = 0; e4 < NEMB / 4; ++e4) {
            float4 wv = wih4[e4];
            float4 m0 = wemb4[4 * e4 + 0];
            float4 m1 = wemb4[4 * e4 + 1];
            float4 m2 = wemb4[4 * e4 + 2];
            float4 m3 = wemb4[4 * e4 + 3];
            wcx += wv.x * m0.x + wv.y * m1.x + wv.z * m2.x + wv.w * m3.x;
            wcy += wv.x * m0.y + wv.y * m1.y + wv.z * m2.y + wv.w * m3.y;
            wcz += wv.x * m0.z + wv.y * m1.z + wv.z * m2.z + wv.w * m3.z;
            wcw += wv.x * m0.w + wv.y * m1.w + wv.z * m2.w + wv.w * m3.w;
            bc  += wv.x * b_emb[4 * e4 + 0] + wv.y * b_emb[4 * e4 + 1]
                 + wv.z * b_emb[4 * e4 + 2] + wv.w * b_emb[4 * e4 + 3];
        }
    }

    // ---- this thread's recurrent weight row (64 floats -> VGPRs) ----
    float whh[NHID];
    {
        const float4* q4 = (const float4*)(W_hh + g * NHID);
        #pragma unroll
        for (int k = 0; k < NHID / 4; ++k) {
            float4 v = q4[k];
            whh[4 * k + 0] = v.x; whh[4 * k + 1] = v.y;
            whh[4 * k + 2] = v.z; whh[4 * k + 3] = v.w;
        }
    }

    __syncthreads();   // s_x, s_h ready

    // ---- recurrence: 64 steps, ONE barrier each, ROLLED loop ----
    float c = 0.0f;    // redundant per-wave copy of c_j
    #pragma unroll 1
    for (int t = 0; t < TT; ++t) {
        const int p = t & 1;
        // gate pre-activation: bc + x[t].wc + h . whh  (4 independent chains)
        const float4 x = ((const float4*)s_x)[t];       // LDS broadcast
        float v0 = bc + x.x * wcx + x.y * wcy;
        float v1 = x.z * wcz + x.w * wcw;
        float v2 = 0.f, v3 = 0.f;
        const float4* h4 = (const float4*)s_h;
        #pragma unroll
        for (int k = 0; k < NHID / 4; ++k) {
            float4 a = h4[k];
            v0 += a.x * whh[4 * k + 0];
            v1 += a.y * whh[4 * k + 1];
            v2 += a.z * whh[4 * k + 2];
            v3 += a.w * whh[4 * k + 3];
        }
        const float v = (v0 + v1) + (v2 + v3);
        const float a = (gtype == 2) ? fast_tanh(v) : fast_sigmoid(v);
        s_act[p][g] = a;
        __syncthreads();

        // redundant update in every wave (bit-identical across waves)
        const float ig = s_act[p][j];
        const float fg = s_act[p][NHID + j];
        const float gg = s_act[p][2 * NHID + j];
        const float og = s_act[p][3 * NHID + j];
        c = fg * c + ig * gg;
        const float h = og * fast_tanh(c);
        s_h[j] = h;                                   // identical values race: benign
        if (tid < NHID) s_hs[t * (NHID + 1) + j] = h; // wave 0 records history
        asm volatile("" ::: "memory");  // compiler fence: no read hoist over the write
        // no 2nd barrier: each wave reads back its OWN s_h writes next step;
        // other waves' writes are identical 32-bit values.
    }
    __syncthreads();   // s_hs complete

    // ---- dump hs to global for kernel 2 (coalesced) ----
    #pragma unroll
    for (int idx = tid; idx < TT * NHID; idx += 256) {
        const int t = idx >> 6, h = idx & 63;
        hs_g[m * (TT * NHID) + idx] = s_hs[t * (NHID + 1) + h];
    }

    // ---- temporal attention pooling (softmax over t, i-independent) ----
    if (tid < TT) {
        const int t = tid;
        float r = 0.0f;
        #pragma unroll
        for (int k = 0; k < NHID; ++k)
            r += s_hs[t * (NHID + 1) + k] * s_war[k];
        float mx = r;
        #pragma unroll
        for (int off = 32; off >= 1; off >>= 1)
            mx = fmaxf(mx, __shfl_xor(mx, off));
        const float e = __expf(r - mx);
        float s = e;
        #pragma unroll
        for (int off = 32; off >= 1; off >>= 1)
            s += __shfl_xor(s, off);
        s_p[t] = __fdividef(e, s);
    }
    __syncthreads();

    if (tid < NHID) {
        float acc = 0.0f;
        #pragma unroll
        for (int t = 0; t < TT; ++t)
            acc += s_p[t] * s_hs[t * (NHID + 1) + tid];
        out[m * (2 * NHID) + tid] = fast_tanh(acc);
    }
}

// ---------------------------------------------------------------------------
// Kernel 2: spatial inverse-distance aggregation (output cols 64..127)
// chsum[b,i,h] = sum_t sum_{j!=i} hs[b,j,t,h] / (dist(i,j,t)+eps)
// Grid: 160 blocks (b*40+i), 256 threads = (t-quarter q, h).
// ---------------------------------------------------------------------------
__global__ __launch_bounds__(256)
void k_spatial(const float* __restrict__ inputs,
               const float* __restrict__ hs_g,
               float* __restrict__ out)
{
    __shared__ float s_w[TT * NN];          // 2560 inverse-distance weights
    __shared__ float s_part[4 * NHID];

    const int bi  = blockIdx.x;
    const int b   = bi / NN;
    const int i   = bi - b * NN;
    const int tid = threadIdx.x;

    for (int idx = tid; idx < TT * NN; idx += 256) {
        const int t = idx / NN;
        const int j = idx - t * NN;
        const float* pi = inputs + ((b * NN + i) * TT + t) * NIN;
        const float* pj = inputs + ((b * NN + j) * TT + t) * NIN;
        const float dx = pi[0] - pj[0];
        const float dy = pi[1] - pj[1];
        const float d  = sqrtf(dx * dx + dy * dy);
        s_w[idx] = (j == i) ? 0.0f : __fdividef(1.0f, d + EPSW);
    }
    __syncthreads();

    const int h = tid & 63;
    const int q = tid >> 6;          // t-quarter

    const float* base = hs_g + (size_t)b * NN * TT * NHID + h;
    float a0 = 0.f, a1 = 0.f, a2 = 0.f, a3 = 0.f;
    for (int t = q * 16; t < q * 16 + 16; ++t) {
        const float* hp = base + t * NHID;
        const float* wp = s_w + t * NN;
        #pragma unroll
        for (int j = 0; j < NN; j += 4) {
            a0 += wp[j + 0] * hp[(size_t)(j + 0) * TT * NHID];
            a1 += wp[j + 1] * hp[(size_t)(j + 1) * TT * NHID];
            a2 += wp[j + 2] * hp[(size_t)(j + 2) * TT * NHID];
            a3 += wp[j + 3] * hp[(size_t)(j + 3) * TT * NHID];
        }
    }
    s_part[q * NHID + h] = (a0 + a1) + (a2 + a3);
    __syncthreads();

    if (tid < NHID) {
        const float s = s_part[tid] + s_part[NHID + tid] +
                        s_part[2 * NHID + tid] + s_part[3 * NHID + tid];
        out[bi * (2 * NHID) + NHID + tid] = fast_tanh(s);
    }
}

extern "C" void kernel_launch(void* const* d_in, const int* in_sizes, int n_in,
                              void* d_out, int out_size, void* d_ws, size_t ws_size,
                              hipStream_t stream) {
    const float* inputs = (const float*)d_in[0];
    // d_in[1..4]: rel_rec / rel_send / rel_rec_t / rel_send_t (one-hot, folded)
    const float* W_emb  = (const float*)d_in[5];
    const float* b_emb  = (const float*)d_in[6];
    const float* W_ih   = (const float*)d_in[7];
    const float* W_hh   = (const float*)d_in[8];
    const float* b_ih   = (const float*)d_in[9];
    const float* b_hh   = (const float*)d_in[10];
    const float* W_att  = (const float*)d_in[11];
    // d_in[12] = b_att: cancels in the softmax, unused.

    float* outp = (float*)d_out;
    float* hs_g = (float*)d_ws;   // 160*64*64 floats = 2.62 MB

    hipLaunchKernelGGL(k_lstm, dim3(BB * NN), dim3(256), 0, stream,
                       inputs, W_emb, b_emb, W_ih, W_hh, b_ih, b_hh, W_att,
                       outp, hs_g);
    hipLaunchKernelGGL(k_spatial, dim3(BB * NN), dim3(256), 0, stream,
                       inputs, hs_g, outp);
}